// Round 28
// baseline (745.682 us; speedup 1.0000x reference)
//
#include <hip/hip_runtime.h>
#include <math.h>

#define DEV __device__ __forceinline__

typedef __attribute__((ext_vector_type(8))) unsigned short u16x8;
typedef __attribute__((ext_vector_type(8))) __bf16 bf16x8;
typedef __attribute__((ext_vector_type(4))) float f32x4;

static constexpr int TOK = 50176;   // 1024 windows * 49 tokens = B*H*W
static constexpr int DIMC = 384;
static constexpr float QSCALE = 0.17677669529663687f;  // 32^-0.5

DEV unsigned short f2bf(float f) {   // native cvt, RNE
  __bf16 h = (__bf16)f;
  return __builtin_bit_cast(unsigned short, h);
}

DEV float bf2f(unsigned short b) {
  union { unsigned u; float f; } v; v.u = ((unsigned)b) << 16; return v.f;
}

DEV f32x4 mfma16(bf16x8 a, bf16x8 b, f32x4 c) {
  return __builtin_amdgcn_mfma_f32_16x16x32_bf16(a, b, c, 0, 0, 0);
}

DEV void gload_lds16(const void* g, void* lds) {
  __builtin_amdgcn_global_load_lds(
      (const __attribute__((address_space(1))) void*)g,
      (__attribute__((address_space(3))) void*)lds, 16, 0, 0);
}

// All 7 weight fp32->bf16 conversions in one launch (segment if-chain on blockIdx).
__global__ __launch_bounds__(256) void w2bf7_kern(
    const float* __restrict__ s0, const float* __restrict__ s1,
    const float* __restrict__ s2, const float* __restrict__ s3,
    const float* __restrict__ s4, const float* __restrict__ s5,
    const float* __restrict__ s6,
    unsigned short* __restrict__ d0, unsigned short* __restrict__ d1,
    unsigned short* __restrict__ d2, unsigned short* __restrict__ d3,
    unsigned short* __restrict__ d4, unsigned short* __restrict__ d5,
    unsigned short* __restrict__ d6) {
  const int b = blockIdx.x;
  const float* src; unsigned short* dst; int off;
  if      (b < 1152) { src = s0; dst = d0; off = b; }
  else if (b < 1728) { src = s1; dst = d1; off = b - 1152; }
  else if (b < 2304) { src = s2; dst = d2; off = b - 1728; }
  else if (b < 4608) { src = s3; dst = d3; off = b - 2304; }
  else if (b < 6912) { src = s4; dst = d4; off = b - 4608; }
  else if (b < 9216) { src = s5; dst = d5; off = b - 6912; }
  else               { src = s6; dst = d6; off = b - 9216; }
  const int i = off * 256 + threadIdx.x;
  dst[i] = f2bf(src[i]);  // all segment sizes are multiples of 256
}

// Fused attention bias: bias[wi][h][i(64)][j(64)] = rpb[rpi[i,j],h] + mask[wi,i,j],
// -1e9 padding outside 49x49.
__global__ __launch_bounds__(256) void bias_kern(const int* __restrict__ rpi,
                                                 const float* __restrict__ mask,
                                                 const float* __restrict__ rpb,
                                                 unsigned short* __restrict__ out) {
  const int wh = blockIdx.x;              // wi*12 + h, 0..3071
  const int wi = wh / 12, h = wh - wi * 12;
  const int t = threadIdx.x;
#pragma unroll
  for (int k = 0; k < 16; ++k) {
    const int idx = k * 256 + t;          // 0..4095
    const int i = idx >> 6, j = idx & 63;
    float v = -1e9f;
    if (i < 49 && j < 49)
      v = rpb[rpi[i * 49 + j] * 12 + h] + mask[(size_t)wi * 2401 + i * 49 + j];
    out[(size_t)wh * 4096 + idx] = f2bf(v);
  }
}

// Single-branch LayerNorm (no window).
__global__ __launch_bounds__(256) void ln_kern(const float* __restrict__ in,
                                               const float* __restrict__ gw,
                                               const float* __restrict__ gb,
                                               unsigned short* __restrict__ out) {
  const int row = blockIdx.x * 4 + (threadIdx.x >> 6);
  const int l = threadIdx.x & 63;
  const float* x = in + (size_t)row * DIMC;
  float v[6]; float s = 0.f, s2 = 0.f;
#pragma unroll
  for (int j = 0; j < 6; ++j) { float t = x[l + 64 * j]; v[j] = t; s += t; s2 += t * t; }
#pragma unroll
  for (int d = 1; d < 64; d <<= 1) { s += __shfl_xor(s, d); s2 += __shfl_xor(s2, d); }
  const float mean = s * (1.f / 384.f);
  const float var = s2 * (1.f / 384.f) - mean * mean;
  const float rs = rsqrtf(var + 1e-5f);
#pragma unroll
  for (int j = 0; j < 6; ++j) {
    int c = l + 64 * j;
    out[(size_t)row * DIMC + c] = f2bf((v[j] - mean) * rs * gw[c] + gb[c]);
  }
}

// Dual-branch LN1 (+roll+window partition), one launch.
__global__ __launch_bounds__(256) void ln2x_win_kern(
    const float* __restrict__ in1, const float* __restrict__ gw1,
    const float* __restrict__ gb1, unsigned short* __restrict__ out1,
    const float* __restrict__ in2, const float* __restrict__ gw2,
    const float* __restrict__ gb2, unsigned short* __restrict__ out2) {
  int row = blockIdx.x * 4 + (threadIdx.x >> 6);
  const int l = threadIdx.x & 63;
  const bool hi = row >= TOK;
  if (hi) row -= TOK;
  const float* in = hi ? in2 : in1;
  const float* gw = hi ? gw2 : gw1;
  const float* gb = hi ? gb2 : gb1;
  unsigned short* out = hi ? out2 : out1;
  const int wq = row / 49, nn = row - wq * 49;
  const int bb = wq >> 8, wi = wq & 255;
  int hh = (wi >> 4) * 7 + nn / 7 + 3;        if (hh >= 112) hh -= 112;
  int cc = (wi & 15) * 7 + (nn - (nn / 7) * 7) + 3; if (cc >= 112) cc -= 112;
  const int src = bb * 12544 + hh * 112 + cc;
  const float* x = in + (size_t)src * DIMC;
  float v[6]; float s = 0.f, s2 = 0.f;
#pragma unroll
  for (int j = 0; j < 6; ++j) { float t = x[l + 64 * j]; v[j] = t; s += t; s2 += t * t; }
#pragma unroll
  for (int d = 1; d < 64; d <<= 1) { s += __shfl_xor(s, d); s2 += __shfl_xor(s2, d); }
  const float mean = s * (1.f / 384.f);
  const float var = s2 * (1.f / 384.f) - mean * mean;
  const float rs = rsqrtf(var + 1e-5f);
#pragma unroll
  for (int j = 0; j < 6; ++j) {
    int c = l + 64 * j;
    out[(size_t)row * DIMC + c] = f2bf((v[j] - mean) * rs * gw[c] + gb[c]);
  }
}

enum { E_BF16 = 0, E_SCATTER = 2, E_GELU = 3, E_RESOUT = 4 };

// C = A(MxK) @ W(NxK)^T + bias.
// VAR=0: 128x128, 3-buf, dist-2, vmcnt(4), 48KB LDS, 3 blk/CU  (~1.5-round grids).
// VAR=1: 256x128, 3-buf, dist-2, vmcnt(6), 72KB LDS, 2 blk/CU  (>=4-round grids).
// FINAL LEDGER: dist-1@5blk=227us (R13), dist-2@3blk=118us (optimum),
// dist-3@2blk=141us (R21) — TLP dominates latency coverage in this family.
// 256x128 @1.15-round worse (R12); merged-MLP/LN2 neutral-neg (R14/R15);
// LN vectorization neutral-neg (R19); setprio removed (m190/R17).
// Nine-times-measured optimum: ~744us (R17/R20/R22-R27).
// Wave-uniform field-wise segment select (rule #20). XOR-swizzle both-sides
// (rule #21). Col-fast decode + bijective XCD swizzle (m204).
template<int EPI, int VAR>
__global__ __launch_bounds__(256, 2) void gemm_bt(
    const unsigned short* __restrict__ A0, const unsigned short* __restrict__ W0,
    const float* __restrict__ bias0, unsigned short* __restrict__ outb0,
    float* __restrict__ outf1_0, float* __restrict__ outf2_0,
    const float* __restrict__ res1_0, const float* __restrict__ res2_0,
    int N0, int nbx0, int ntiles0, float scale0,
    const unsigned short* __restrict__ A1, const unsigned short* __restrict__ W1,
    const float* __restrict__ bias1, unsigned short* __restrict__ outb1,
    float* __restrict__ outf1_1, float* __restrict__ outf2_1,
    const float* __restrict__ res1_1, const float* __restrict__ res2_1,
    int N1, int nbx1, float scale1,
    int K) {
  constexpr int MROWS = VAR ? 256 : 128;   // M-tile
  constexpr int MT = VAR ? 8 : 4;          // 16-row frags per wave
  constexpr int AIT = VAR ? 4 : 2;         // 64-row staging rounds for A
  __shared__ __align__(16) unsigned short sA[3][MROWS * 32];
  __shared__ __align__(16) unsigned short sB[3][128 * 32];
  const int t = threadIdx.x;
  const int wv = t >> 6, l = t & 63;
  const int wm = (wv >> 1) * (VAR ? 128 : 64), wn = (wv & 1) * 64;

  const int total = gridDim.x;
  const int q = total >> 3, rr8 = total & 7;
  const int xcd = blockIdx.x & 7, lid = blockIdx.x >> 3;
  const int wgid = (xcd < rr8 ? xcd * (q + 1) : rr8 * (q + 1) + (xcd - rr8) * q) + lid;

  // wave-uniform field-wise segment select (stays in SGPRs)
  const bool sel = wgid >= ntiles0;
  const unsigned short* A = sel ? A1 : A0;
  const unsigned short* W = sel ? W1 : W0;
  const float* bias = sel ? bias1 : bias0;
  unsigned short* outb = sel ? outb1 : outb0;
  float* outf1 = sel ? outf1_1 : outf1_0;
  float* outf2 = sel ? outf2_1 : outf2_0;
  const float* res1 = sel ? res1_1 : res1_0;
  const float* res2 = sel ? res2_1 : res2_0;
  const int N = sel ? N1 : N0;
  const int nbx = sel ? nbx1 : nbx0;
  const float scale = sel ? scale1 : scale0;
  const int local = wgid - (sel ? ntiles0 : 0);
  const int n0 = (local % nbx) * 128, m0 = (local / nbx) * MROWS;

  const int srow = t >> 2;                                  // 0..63
  const int scol = ((t & 3) ^ ((t >> 3) & 3)) * 8;          // pre-swizzled src col

  f32x4 acc[MT][4];
  const f32x4 fzero = {0.f, 0.f, 0.f, 0.f};
#pragma unroll
  for (int i = 0; i < MT; ++i)
#pragma unroll
    for (int j = 0; j < 4; ++j) acc[i][j] = fzero;

  const unsigned short* gA = A + (size_t)(m0 + srow) * K + scol;
  const unsigned short* gB = W + (size_t)(n0 + srow) * K + scol;
  const int ldsW = wv * 512;

  const int g = l >> 4, lr = l & 15;
  const int swz = ((lr >> 1) & 3) << 4;  // read-side XOR (bytes)

  const int ntt = K >> 5;
#pragma unroll
  for (int p = 0; p < 2; ++p) {
#pragma unroll
    for (int it = 0; it < AIT; ++it)
      gload_lds16(gA + (size_t)(it * 64) * K + p * 32, &sA[p][it * 2048 + ldsW]);
#pragma unroll
    for (int it = 0; it < 2; ++it)
      gload_lds16(gB + (size_t)(it * 64) * K + p * 32, &sB[p][it * 2048 + ldsW]);
  }
  for (int tt = 0; tt < ntt; ++tt) {
    if (tt + 1 < ntt) {
      if constexpr (VAR) {
        asm volatile("s_waitcnt vmcnt(6)" ::: "memory");
      } else {
        asm volatile("s_waitcnt vmcnt(4)" ::: "memory");
      }
    } else {
      asm volatile("s_waitcnt vmcnt(0)" ::: "memory");
    }
    __builtin_amdgcn_s_barrier();
    asm volatile("" ::: "memory");
    if (tt + 2 < ntt) {
      const int kt = (tt + 2) << 5;
      const int b2 = (tt + 2) % 3;
#pragma unroll
      for (int it = 0; it < AIT; ++it)
        gload_lds16(gA + (size_t)(it * 64) * K + kt, &sA[b2][it * 2048 + ldsW]);
#pragma unroll
      for (int it = 0; it < 2; ++it)
        gload_lds16(gB + (size_t)(it * 64) * K + kt, &sB[b2][it * 2048 + ldsW]);
    }
    const int cb = tt % 3;
    const char* bA = (const char*)&sA[cb][0];
    const char* bB = (const char*)&sB[cb][0];
    bf16x8 af[MT], bff[4];
#pragma unroll
    for (int mt = 0; mt < MT; ++mt)
      af[mt] = *(const bf16x8*)(bA + (wm + mt * 16 + lr) * 64 + ((g * 16) ^ swz));
#pragma unroll
    for (int nt2 = 0; nt2 < 4; ++nt2)
      bff[nt2] = *(const bf16x8*)(bB + (wn + nt2 * 16 + lr) * 64 + ((g * 16) ^ swz));
#pragma unroll
    for (int mt = 0; mt < MT; ++mt)
#pragma unroll
      for (int nt2 = 0; nt2 < 4; ++nt2)
        acc[mt][nt2] = mfma16(af[mt], bff[nt2], acc[mt][nt2]);
    asm volatile("" ::: "memory");
  }

  const int col = lr;
#pragma unroll
  for (int mt = 0; mt < MT; ++mt) {
#pragma unroll
    for (int r = 0; r < 4; ++r) {
      const int m = m0 + wm + mt * 16 + g * 4 + r;
      size_t obase = 0;
      if constexpr (EPI == E_SCATTER) {  // window-reverse + roll(+3,+3)
        int wq = m / 49, nn = m - wq * 49;
        int bb = wq >> 8, wi = wq & 255;
        int hh = (wi >> 4) * 7 + nn / 7 + 3;        if (hh >= 112) hh -= 112;
        int cc = (wi & 15) * 7 + (nn - (nn / 7) * 7) + 3; if (cc >= 112) cc -= 112;
        obase = ((size_t)bb * 12544 + hh * 112 + cc) * 384;
      }
#pragma unroll
      for (int nt2 = 0; nt2 < 4; ++nt2) {
        const int j = n0 + wn + nt2 * 16 + col;
        float v = acc[mt][nt2][r] + bias[j];
        if constexpr (EPI == E_BF16) {
          outb[(size_t)m * N + j] = f2bf(v * scale);
        } else if constexpr (EPI == E_GELU) {
          // tanh-form GELU with fast rcp (|dev| < 5e-4, bf16-safe)
          float z = v * (1.5957691216057308f + 0.0713548162726009f * v * v);
          float e = __expf(-z);
          float gg = v * __builtin_amdgcn_rcpf(1.f + e);
          outb[(size_t)m * N + j] = f2bf(gg);
        } else if constexpr (EPI == E_SCATTER) {
          outf1[obase + j] = res1[obase + j] + v;
          outf2[obase + j] = res2[obase + j] + v;
        } else {  // E_RESOUT: fp32 final output = mlp + residual (in-place)
          outf1[(size_t)m * N + j] = v + res1[(size_t)m * N + j];
        }
      }
    }
  }
}

// One block per (window, head). S = (q2*scale) @ k1^T + bias(LDS), softmax, O = P @ v1.
__global__ __launch_bounds__(256) void attn_kern(
    const unsigned short* __restrict__ q2,    // TOK x 384 (already *SCALE)
    const unsigned short* __restrict__ kv1,   // TOK x 768 (k | v)
    const unsigned short* __restrict__ biasb, // 256 x 12 x 64 x 64 bf16
    unsigned short* __restrict__ o) {         // TOK x 384
  const int w = blockIdx.x, h = blockIdx.y;
  __shared__ __align__(16) unsigned short sQ[64 * 32];
  __shared__ __align__(16) unsigned short sK[64 * 32];
  __shared__ __align__(16) unsigned short sVT[32 * 64];   // V^T: [n][k]
  __shared__ __align__(16) unsigned short sP[64 * 64];
  __shared__ __align__(16) unsigned short sBias[64 * 64];
  const int t = threadIdx.x, wv = t >> 6, l = t & 63;
  const int r = t >> 2, c = (t & 3) * 8;
  const u16x8 z8 = {0, 0, 0, 0, 0, 0, 0, 0};
  const unsigned short* bsrc = biasb + (((size_t)(w & 255) * 12 + h) << 12);
  *(u16x8*)&sBias[t * 8] = *(const u16x8*)&bsrc[t * 8];
  *(u16x8*)&sBias[2048 + t * 8] = *(const u16x8*)&bsrc[2048 + t * 8];
  if (r < 49) {
    *(u16x8*)&sQ[r * 32 + c] = *(const u16x8*)&q2[((size_t)w * 49 + r) * 384 + h * 32 + c];
    *(u16x8*)&sK[r * 32 + c] = *(const u16x8*)&kv1[((size_t)w * 49 + r) * 768 + h * 32 + c];
    u16x8 vv = *(const u16x8*)&kv1[((size_t)w * 49 + r) * 768 + 384 + h * 32 + c];
#pragma unroll
    for (int e = 0; e < 8; ++e) sVT[(c + e) * 64 + r] = vv[e];
  } else {
    *(u16x8*)&sQ[r * 32 + c] = z8;
    *(u16x8*)&sK[r * 32 + c] = z8;
#pragma unroll
    for (int e = 0; e < 8; ++e) sVT[(c + e) * 64 + r] = 0;
  }
  __syncthreads();

  const int g = l >> 4, col = l & 15;
  const f32x4 fzero = {0.f, 0.f, 0.f, 0.f};
  bf16x8 aq = *(const bf16x8*)&sQ[(wv * 16 + col) * 32 + g * 8];
  f32x4 s[4];
#pragma unroll
  for (int nt = 0; nt < 4; ++nt) {
    bf16x8 bk = *(const bf16x8*)&sK[(nt * 16 + col) * 32 + g * 8];
    s[nt] = mfma16(aq, bk, fzero);
  }

  float p[4][4];
#pragma unroll
  for (int rr = 0; rr < 4; ++rr) {
    const int i = wv * 16 + g * 4 + rr;
    float mx = -1e30f;
#pragma unroll
    for (int nt = 0; nt < 4; ++nt) {
      const int j = nt * 16 + col;
      float val = s[nt][rr] + bf2f(sBias[i * 64 + j]);
      p[nt][rr] = val;
      mx = fmaxf(mx, val);
    }
#pragma unroll
    for (int d = 1; d < 16; d <<= 1) mx = fmaxf(mx, __shfl_xor(mx, d));
    float sm = 0.f;
#pragma unroll
    for (int nt = 0; nt < 4; ++nt) {
      float e = __expf(p[nt][rr] - mx);
      p[nt][rr] = e; sm += e;
    }
#pragma unroll
    for (int d = 1; d < 16; d <<= 1) sm += __shfl_xor(sm, d);
    const float inv = __builtin_amdgcn_rcpf(sm);
#pragma unroll
    for (int nt = 0; nt < 4; ++nt) p[nt][rr] *= inv;
  }
#pragma unroll
  for (int rr = 0; rr < 4; ++rr) {
    const int i = wv * 16 + g * 4 + rr;
#pragma unroll
    for (int nt = 0; nt < 4; ++nt) sP[i * 64 + nt * 16 + col] = f2bf(p[nt][rr]);
  }
  __syncthreads();

  f32x4 oa[2] = {fzero, fzero};
#pragma unroll
  for (int ks = 0; ks < 2; ++ks) {
    bf16x8 ap = *(const bf16x8*)&sP[(wv * 16 + col) * 64 + ks * 32 + g * 8];
#pragma unroll
    for (int n2 = 0; n2 < 2; ++n2) {
      bf16x8 bv = *(const bf16x8*)&sVT[(n2 * 16 + col) * 64 + ks * 32 + g * 8];
      oa[n2] = mfma16(ap, bv, oa[n2]);
    }
  }
#pragma unroll
  for (int rr = 0; rr < 4; ++rr) {
    const int i = wv * 16 + g * 4 + rr;
    if (i < 49) {
#pragma unroll
      for (int n2 = 0; n2 < 2; ++n2)
        o[((size_t)w * 49 + i) * 384 + h * 32 + n2 * 16 + col] = f2bf(oa[n2][rr]);
    }
  }
}

extern "C" void kernel_launch(void* const* d_in, const int* in_sizes, int n_in,
                              void* d_out, int out_size, void* d_ws, size_t ws_size,
                              hipStream_t stream) {
  (void)in_sizes; (void)n_in; (void)out_size; (void)ws_size;
  const float* s1   = (const float*)d_in[0];
  const float* s2   = (const float*)d_in[1];
  const float* mask = (const float*)d_in[2];
  const int*   rpi  = (const int*)d_in[3];
  const float* n1w1 = (const float*)d_in[4],  *n1b1 = (const float*)d_in[5];
  const float* n1w2 = (const float*)d_in[6],  *n1b2 = (const float*)d_in[7];
  const float* qw1  = (const float*)d_in[8],  *qb1  = (const float*)d_in[9];
  const float* qw2  = (const float*)d_in[10], *qb2  = (const float*)d_in[11];
  const float* rpb1 = (const float*)d_in[12];
  const float* pw1  = (const float*)d_in[14], *pb1  = (const float*)d_in[15];
  const float* n2w1 = (const float*)d_in[18], *n2b1 = (const float*)d_in[19];
  const float* n2w2 = (const float*)d_in[20], *n2b2 = (const float*)d_in[21];
  const float* m1fc1w = (const float*)d_in[22], *m1fc1b = (const float*)d_in[23];
  const float* m1fc2w = (const float*)d_in[24], *m1fc2b = (const float*)d_in[25];
  const float* m2fc1w = (const float*)d_in[26], *m2fc1b = (const float*)d_in[27];
  const float* m2fc2w = (const float*)d_in[28], *m2fc2b = (const float*)d_in[29];

  // R6-PROVEN layout: total = 5*S1 + 5.9MB ~= 198.6 MB (R7 lesson: don't exceed).
  char* ws = (char*)d_ws;
  const size_t S1 = (size_t)TOK * DIMC * 2;  // 38,535,168 B
  unsigned short* x1w  = (unsigned short*)(ws);        // later: obuf, xm
  unsigned short* x2w  = (unsigned short*)(ws + S1);   // later: biasb, then hbuf
  unsigned short* kv1  = (unsigned short*)(ws + 2 * S1);
  unsigned short* q2b  = (unsigned short*)(ws + 4 * S1);
  unsigned short* obuf = x1w;
  unsigned short* biasb = x2w;  // 25.2 MB <= S1
  unsigned short* hbuf = x2w;   // TOK x 1536 bf16 = 4*S1 (S1..5S1), overlays dead bufs
  unsigned short* xm   = x1w;
  char* wp = ws + 5 * S1;
  unsigned short* wq1b = (unsigned short*)(wp);
  unsigned short* wq2b = (unsigned short*)(wp + 589824);
  unsigned short* wp1b = (unsigned short*)(wp + 884736);
  unsigned short* wf11 = (unsigned short*)(wp + 1179648);
  unsigned short* wf12 = (unsigned short*)(wp + 2359296);
  unsigned short* wf21 = (unsigned short*)(wp + 3538944);
  unsigned short* wf22 = (unsigned short*)(wp + 4718592);

  float* outf = (float*)d_out;
  float* b1 = outf;
  float* b2 = outf + (size_t)19267584;

  // weights fp32 -> bf16 (qw1: k|v rows 384..1151 only)
  w2bf7_kern<<<11520, 256, 0, stream>>>(qw1 + 384 * 384, qw2, pw1,
                                        m1fc1w, m1fc2w, m2fc1w, m2fc2w,
                                        wq1b, wq2b, wp1b, wf11, wf12, wf21, wf22);

  // LN1 both branches + roll + window partition (one launch)
  ln2x_win_kern<<<2 * TOK / 4, 256, 0, stream>>>(s1, n1w1, n1b1, x1w,
                                                 s2, n1w2, n1b2, x2w);

  // merged qkv (seg0) + q2 (seg1, pre-scaled), 256-row tiles (VAR=1)
  gemm_bt<E_BF16, 1><<<1764, 256, 0, stream>>>(
      x1w, wq1b, qb1 + 384, kv1, nullptr, nullptr, nullptr, nullptr, 768, 6, 1176, 1.0f,
      x2w, wq2b, qb2, q2b, nullptr, nullptr, nullptr, nullptr, 384, 3, QSCALE, 384);

  // fused attention bias table (x2w now dead) then attention
  bias_kern<<<3072, 256, 0, stream>>>(rpi, mask, rpb1, biasb);
  attn_kern<<<dim3(1024, 12), 256, 0, stream>>>(q2b, kv1, biasb, obuf);

  // projection + window-reverse scatter + both residuals (VAR=0)
  gemm_bt<E_SCATTER, 0><<<1176, 256, 0, stream>>>(
      obuf, wp1b, pb1, nullptr, b1, b2, s1, s2, 384, 3, 1176, 1.0f,
      obuf, wp1b, pb1, nullptr, b1, b2, s1, s2, 384, 3, 1.0f, 384);

  // branch 1 MLP (fc1 VAR=1; fc2 VAR=0 — proven configs)
  ln_kern<<<TOK / 4, 256, 0, stream>>>(b1, n2w1, n2b1, xm);
  gemm_bt<E_GELU, 1><<<2352, 256, 0, stream>>>(
      xm, wf11, m1fc1b, hbuf, nullptr, nullptr, nullptr, nullptr, 1536, 12, 2352, 1.0f,
      xm, wf11, m1fc1b, hbuf, nullptr, nullptr, nullptr, nullptr, 1536, 12, 1.0f, 384);
  gemm_bt<E_RESOUT, 0><<<1176, 256, 0, stream>>>(
      hbuf, wf12, m1fc2b, nullptr, b1, nullptr, b1, nullptr, 384, 3, 1176, 1.0f,
      hbuf, wf12, m1fc2b, nullptr, b1, nullptr, b1, nullptr, 384, 3, 1.0f, 1536);

  // branch 2 MLP
  ln_kern<<<TOK / 4, 256, 0, stream>>>(b2, n2w2, n2b2, xm);
  gemm_bt<E_GELU, 1><<<2352, 256, 0, stream>>>(
      xm, wf21, m2fc1b, hbuf, nullptr, nullptr, nullptr, nullptr, 1536, 12, 2352, 1.0f,
      xm, wf21, m2fc1b, hbuf, nullptr, nullptr, nullptr, nullptr, 1536, 12, 1.0f, 384);
  gemm_bt<E_RESOUT, 0><<<1176, 256, 0, stream>>>(
      hbuf, wf22, m2fc2b, nullptr, b2, nullptr, b2, nullptr, 384, 3, 1176, 1.0f,
      hbuf, wf22, m2fc2b, nullptr, b2, nullptr, b2, nullptr, 384, 3, 1.0f, 1536);
}

// Round 29
// 740.904 us; speedup vs baseline: 1.0064x; 1.0064x over previous
//
#include <hip/hip_runtime.h>
#include <math.h>

#define DEV __device__ __forceinline__

typedef __attribute__((ext_vector_type(8))) unsigned short u16x8;
typedef __attribute__((ext_vector_type(8))) __bf16 bf16x8;
typedef __attribute__((ext_vector_type(4))) float f32x4;

static constexpr int TOK = 50176;   // 1024 windows * 49 tokens = B*H*W
static constexpr int DIMC = 384;
static constexpr float QSCALE = 0.17677669529663687f;  // 32^-0.5

DEV unsigned short f2bf(float f) {   // native cvt, RNE
  __bf16 h = (__bf16)f;
  return __builtin_bit_cast(unsigned short, h);
}

DEV float bf2f(unsigned short b) {
  union { unsigned u; float f; } v; v.u = ((unsigned)b) << 16; return v.f;
}

DEV f32x4 mfma16(bf16x8 a, bf16x8 b, f32x4 c) {
  return __builtin_amdgcn_mfma_f32_16x16x32_bf16(a, b, c, 0, 0, 0);
}

DEV void gload_lds16(const void* g, void* lds) {
  __builtin_amdgcn_global_load_lds(
      (const __attribute__((address_space(1))) void*)g,
      (__attribute__((address_space(3))) void*)lds, 16, 0, 0);
}

// All 7 weight fp32->bf16 conversions in one launch (segment if-chain on blockIdx).
__global__ __launch_bounds__(256) void w2bf7_kern(
    const float* __restrict__ s0, const float* __restrict__ s1,
    const float* __restrict__ s2, const float* __restrict__ s3,
    const float* __restrict__ s4, const float* __restrict__ s5,
    const float* __restrict__ s6,
    unsigned short* __restrict__ d0, unsigned short* __restrict__ d1,
    unsigned short* __restrict__ d2, unsigned short* __restrict__ d3,
    unsigned short* __restrict__ d4, unsigned short* __restrict__ d5,
    unsigned short* __restrict__ d6) {
  const int b = blockIdx.x;
  const float* src; unsigned short* dst; int off;
  if      (b < 1152) { src = s0; dst = d0; off = b; }
  else if (b < 1728) { src = s1; dst = d1; off = b - 1152; }
  else if (b < 2304) { src = s2; dst = d2; off = b - 1728; }
  else if (b < 4608) { src = s3; dst = d3; off = b - 2304; }
  else if (b < 6912) { src = s4; dst = d4; off = b - 4608; }
  else if (b < 9216) { src = s5; dst = d5; off = b - 6912; }
  else               { src = s6; dst = d6; off = b - 9216; }
  const int i = off * 256 + threadIdx.x;
  dst[i] = f2bf(src[i]);  // all segment sizes are multiples of 256
}

// Fused attention bias: bias[wi][h][i(64)][j(64)] = rpb[rpi[i,j],h] + mask[wi,i,j],
// -1e9 padding outside 49x49.
__global__ __launch_bounds__(256) void bias_kern(const int* __restrict__ rpi,
                                                 const float* __restrict__ mask,
                                                 const float* __restrict__ rpb,
                                                 unsigned short* __restrict__ out) {
  const int wh = blockIdx.x;              // wi*12 + h, 0..3071
  const int wi = wh / 12, h = wh - wi * 12;
  const int t = threadIdx.x;
#pragma unroll
  for (int k = 0; k < 16; ++k) {
    const int idx = k * 256 + t;          // 0..4095
    const int i = idx >> 6, j = idx & 63;
    float v = -1e9f;
    if (i < 49 && j < 49)
      v = rpb[rpi[i * 49 + j] * 12 + h] + mask[(size_t)wi * 2401 + i * 49 + j];
    out[(size_t)wh * 4096 + idx] = f2bf(v);
  }
}

// Single-branch LayerNorm (no window).
__global__ __launch_bounds__(256) void ln_kern(const float* __restrict__ in,
                                               const float* __restrict__ gw,
                                               const float* __restrict__ gb,
                                               unsigned short* __restrict__ out) {
  const int row = blockIdx.x * 4 + (threadIdx.x >> 6);
  const int l = threadIdx.x & 63;
  const float* x = in + (size_t)row * DIMC;
  float v[6]; float s = 0.f, s2 = 0.f;
#pragma unroll
  for (int j = 0; j < 6; ++j) { float t = x[l + 64 * j]; v[j] = t; s += t; s2 += t * t; }
#pragma unroll
  for (int d = 1; d < 64; d <<= 1) { s += __shfl_xor(s, d); s2 += __shfl_xor(s2, d); }
  const float mean = s * (1.f / 384.f);
  const float var = s2 * (1.f / 384.f) - mean * mean;
  const float rs = rsqrtf(var + 1e-5f);
#pragma unroll
  for (int j = 0; j < 6; ++j) {
    int c = l + 64 * j;
    out[(size_t)row * DIMC + c] = f2bf((v[j] - mean) * rs * gw[c] + gb[c]);
  }
}

// Dual-branch LN1 (+roll+window partition), one launch.
__global__ __launch_bounds__(256) void ln2x_win_kern(
    const float* __restrict__ in1, const float* __restrict__ gw1,
    const float* __restrict__ gb1, unsigned short* __restrict__ out1,
    const float* __restrict__ in2, const float* __restrict__ gw2,
    const float* __restrict__ gb2, unsigned short* __restrict__ out2) {
  int row = blockIdx.x * 4 + (threadIdx.x >> 6);
  const int l = threadIdx.x & 63;
  const bool hi = row >= TOK;
  if (hi) row -= TOK;
  const float* in = hi ? in2 : in1;
  const float* gw = hi ? gw2 : gw1;
  const float* gb = hi ? gb2 : gb1;
  unsigned short* out = hi ? out2 : out1;
  const int wq = row / 49, nn = row - wq * 49;
  const int bb = wq >> 8, wi = wq & 255;
  int hh = (wi >> 4) * 7 + nn / 7 + 3;        if (hh >= 112) hh -= 112;
  int cc = (wi & 15) * 7 + (nn - (nn / 7) * 7) + 3; if (cc >= 112) cc -= 112;
  const int src = bb * 12544 + hh * 112 + cc;
  const float* x = in + (size_t)src * DIMC;
  float v[6]; float s = 0.f, s2 = 0.f;
#pragma unroll
  for (int j = 0; j < 6; ++j) { float t = x[l + 64 * j]; v[j] = t; s += t; s2 += t * t; }
#pragma unroll
  for (int d = 1; d < 64; d <<= 1) { s += __shfl_xor(s, d); s2 += __shfl_xor(s2, d); }
  const float mean = s * (1.f / 384.f);
  const float var = s2 * (1.f / 384.f) - mean * mean;
  const float rs = rsqrtf(var + 1e-5f);
#pragma unroll
  for (int j = 0; j < 6; ++j) {
    int c = l + 64 * j;
    out[(size_t)row * DIMC + c] = f2bf((v[j] - mean) * rs * gw[c] + gb[c]);
  }
}

enum { E_BF16 = 0, E_SCATTER = 2, E_GELU = 3, E_RESOUT = 4 };

// C = A(MxK) @ W(NxK)^T + bias.
// VAR=0: 128x128, 3-buf, dist-2, vmcnt(4), 48KB LDS, 3 blk/CU  (~1.5-round grids).
// VAR=1: 256x128, 3-buf, dist-2, vmcnt(6), 72KB LDS, 2 blk/CU  (>=4-round grids).
// FINAL LEDGER: dist-1@5blk=227us (R13), dist-2@3blk=118us (optimum),
// dist-3@2blk=141us (R21) — TLP dominates latency coverage in this family.
// 256x128 @1.15-round worse (R12); merged-MLP/LN2 neutral-neg (R14/R15);
// LN vectorization neutral-neg (R19); setprio removed (m190/R17).
// Ten-times-measured optimum: ~744us (R17/R20/R22-R28).
// Wave-uniform field-wise segment select (rule #20). XOR-swizzle both-sides
// (rule #21). Col-fast decode + bijective XCD swizzle (m204).
template<int EPI, int VAR>
__global__ __launch_bounds__(256, 2) void gemm_bt(
    const unsigned short* __restrict__ A0, const unsigned short* __restrict__ W0,
    const float* __restrict__ bias0, unsigned short* __restrict__ outb0,
    float* __restrict__ outf1_0, float* __restrict__ outf2_0,
    const float* __restrict__ res1_0, const float* __restrict__ res2_0,
    int N0, int nbx0, int ntiles0, float scale0,
    const unsigned short* __restrict__ A1, const unsigned short* __restrict__ W1,
    const float* __restrict__ bias1, unsigned short* __restrict__ outb1,
    float* __restrict__ outf1_1, float* __restrict__ outf2_1,
    const float* __restrict__ res1_1, const float* __restrict__ res2_1,
    int N1, int nbx1, float scale1,
    int K) {
  constexpr int MROWS = VAR ? 256 : 128;   // M-tile
  constexpr int MT = VAR ? 8 : 4;          // 16-row frags per wave
  constexpr int AIT = VAR ? 4 : 2;         // 64-row staging rounds for A
  __shared__ __align__(16) unsigned short sA[3][MROWS * 32];
  __shared__ __align__(16) unsigned short sB[3][128 * 32];
  const int t = threadIdx.x;
  const int wv = t >> 6, l = t & 63;
  const int wm = (wv >> 1) * (VAR ? 128 : 64), wn = (wv & 1) * 64;

  const int total = gridDim.x;
  const int q = total >> 3, rr8 = total & 7;
  const int xcd = blockIdx.x & 7, lid = blockIdx.x >> 3;
  const int wgid = (xcd < rr8 ? xcd * (q + 1) : rr8 * (q + 1) + (xcd - rr8) * q) + lid;

  // wave-uniform field-wise segment select (stays in SGPRs)
  const bool sel = wgid >= ntiles0;
  const unsigned short* A = sel ? A1 : A0;
  const unsigned short* W = sel ? W1 : W0;
  const float* bias = sel ? bias1 : bias0;
  unsigned short* outb = sel ? outb1 : outb0;
  float* outf1 = sel ? outf1_1 : outf1_0;
  float* outf2 = sel ? outf2_1 : outf2_0;
  const float* res1 = sel ? res1_1 : res1_0;
  const float* res2 = sel ? res2_1 : res2_0;
  const int N = sel ? N1 : N0;
  const int nbx = sel ? nbx1 : nbx0;
  const float scale = sel ? scale1 : scale0;
  const int local = wgid - (sel ? ntiles0 : 0);
  const int n0 = (local % nbx) * 128, m0 = (local / nbx) * MROWS;

  const int srow = t >> 2;                                  // 0..63
  const int scol = ((t & 3) ^ ((t >> 3) & 3)) * 8;          // pre-swizzled src col

  f32x4 acc[MT][4];
  const f32x4 fzero = {0.f, 0.f, 0.f, 0.f};
#pragma unroll
  for (int i = 0; i < MT; ++i)
#pragma unroll
    for (int j = 0; j < 4; ++j) acc[i][j] = fzero;

  const unsigned short* gA = A + (size_t)(m0 + srow) * K + scol;
  const unsigned short* gB = W + (size_t)(n0 + srow) * K + scol;
  const int ldsW = wv * 512;

  const int g = l >> 4, lr = l & 15;
  const int swz = ((lr >> 1) & 3) << 4;  // read-side XOR (bytes)

  const int ntt = K >> 5;
#pragma unroll
  for (int p = 0; p < 2; ++p) {
#pragma unroll
    for (int it = 0; it < AIT; ++it)
      gload_lds16(gA + (size_t)(it * 64) * K + p * 32, &sA[p][it * 2048 + ldsW]);
#pragma unroll
    for (int it = 0; it < 2; ++it)
      gload_lds16(gB + (size_t)(it * 64) * K + p * 32, &sB[p][it * 2048 + ldsW]);
  }
  for (int tt = 0; tt < ntt; ++tt) {
    if (tt + 1 < ntt) {
      if constexpr (VAR) {
        asm volatile("s_waitcnt vmcnt(6)" ::: "memory");
      } else {
        asm volatile("s_waitcnt vmcnt(4)" ::: "memory");
      }
    } else {
      asm volatile("s_waitcnt vmcnt(0)" ::: "memory");
    }
    __builtin_amdgcn_s_barrier();
    asm volatile("" ::: "memory");
    if (tt + 2 < ntt) {
      const int kt = (tt + 2) << 5;
      const int b2 = (tt + 2) % 3;
#pragma unroll
      for (int it = 0; it < AIT; ++it)
        gload_lds16(gA + (size_t)(it * 64) * K + kt, &sA[b2][it * 2048 + ldsW]);
#pragma unroll
      for (int it = 0; it < 2; ++it)
        gload_lds16(gB + (size_t)(it * 64) * K + kt, &sB[b2][it * 2048 + ldsW]);
    }
    const int cb = tt % 3;
    const char* bA = (const char*)&sA[cb][0];
    const char* bB = (const char*)&sB[cb][0];
    bf16x8 af[MT], bff[4];
#pragma unroll
    for (int mt = 0; mt < MT; ++mt)
      af[mt] = *(const bf16x8*)(bA + (wm + mt * 16 + lr) * 64 + ((g * 16) ^ swz));
#pragma unroll
    for (int nt2 = 0; nt2 < 4; ++nt2)
      bff[nt2] = *(const bf16x8*)(bB + (wn + nt2 * 16 + lr) * 64 + ((g * 16) ^ swz));
#pragma unroll
    for (int mt = 0; mt < MT; ++mt)
#pragma unroll
      for (int nt2 = 0; nt2 < 4; ++nt2)
        acc[mt][nt2] = mfma16(af[mt], bff[nt2], acc[mt][nt2]);
    asm volatile("" ::: "memory");
  }

  const int col = lr;
#pragma unroll
  for (int mt = 0; mt < MT; ++mt) {
#pragma unroll
    for (int r = 0; r < 4; ++r) {
      const int m = m0 + wm + mt * 16 + g * 4 + r;
      size_t obase = 0;
      if constexpr (EPI == E_SCATTER) {  // window-reverse + roll(+3,+3)
        int wq = m / 49, nn = m - wq * 49;
        int bb = wq >> 8, wi = wq & 255;
        int hh = (wi >> 4) * 7 + nn / 7 + 3;        if (hh >= 112) hh -= 112;
        int cc = (wi & 15) * 7 + (nn - (nn / 7) * 7) + 3; if (cc >= 112) cc -= 112;
        obase = ((size_t)bb * 12544 + hh * 112 + cc) * 384;
      }
#pragma unroll
      for (int nt2 = 0; nt2 < 4; ++nt2) {
        const int j = n0 + wn + nt2 * 16 + col;
        float v = acc[mt][nt2][r] + bias[j];
        if constexpr (EPI == E_BF16) {
          outb[(size_t)m * N + j] = f2bf(v * scale);
        } else if constexpr (EPI == E_GELU) {
          // tanh-form GELU with fast rcp (|dev| < 5e-4, bf16-safe)
          float z = v * (1.5957691216057308f + 0.0713548162726009f * v * v);
          float e = __expf(-z);
          float gg = v * __builtin_amdgcn_rcpf(1.f + e);
          outb[(size_t)m * N + j] = f2bf(gg);
        } else if constexpr (EPI == E_SCATTER) {
          outf1[obase + j] = res1[obase + j] + v;
          outf2[obase + j] = res2[obase + j] + v;
        } else {  // E_RESOUT: fp32 final output = mlp + residual (in-place)
          outf1[(size_t)m * N + j] = v + res1[(size_t)m * N + j];
        }
      }
    }
  }
}

// One block per (window, head). S = (q2*scale) @ k1^T + bias(LDS), softmax, O = P @ v1.
__global__ __launch_bounds__(256) void attn_kern(
    const unsigned short* __restrict__ q2,    // TOK x 384 (already *SCALE)
    const unsigned short* __restrict__ kv1,   // TOK x 768 (k | v)
    const unsigned short* __restrict__ biasb, // 256 x 12 x 64 x 64 bf16
    unsigned short* __restrict__ o) {         // TOK x 384
  const int w = blockIdx.x, h = blockIdx.y;
  __shared__ __align__(16) unsigned short sQ[64 * 32];
  __shared__ __align__(16) unsigned short sK[64 * 32];
  __shared__ __align__(16) unsigned short sVT[32 * 64];   // V^T: [n][k]
  __shared__ __align__(16) unsigned short sP[64 * 64];
  __shared__ __align__(16) unsigned short sBias[64 * 64];
  const int t = threadIdx.x, wv = t >> 6, l = t & 63;
  const int r = t >> 2, c = (t & 3) * 8;
  const u16x8 z8 = {0, 0, 0, 0, 0, 0, 0, 0};
  const unsigned short* bsrc = biasb + (((size_t)(w & 255) * 12 + h) << 12);
  *(u16x8*)&sBias[t * 8] = *(const u16x8*)&bsrc[t * 8];
  *(u16x8*)&sBias[2048 + t * 8] = *(const u16x8*)&bsrc[2048 + t * 8];
  if (r < 49) {
    *(u16x8*)&sQ[r * 32 + c] = *(const u16x8*)&q2[((size_t)w * 49 + r) * 384 + h * 32 + c];
    *(u16x8*)&sK[r * 32 + c] = *(const u16x8*)&kv1[((size_t)w * 49 + r) * 768 + h * 32 + c];
    u16x8 vv = *(const u16x8*)&kv1[((size_t)w * 49 + r) * 768 + 384 + h * 32 + c];
#pragma unroll
    for (int e = 0; e < 8; ++e) sVT[(c + e) * 64 + r] = vv[e];
  } else {
    *(u16x8*)&sQ[r * 32 + c] = z8;
    *(u16x8*)&sK[r * 32 + c] = z8;
#pragma unroll
    for (int e = 0; e < 8; ++e) sVT[(c + e) * 64 + r] = 0;
  }
  __syncthreads();

  const int g = l >> 4, col = l & 15;
  const f32x4 fzero = {0.f, 0.f, 0.f, 0.f};
  bf16x8 aq = *(const bf16x8*)&sQ[(wv * 16 + col) * 32 + g * 8];
  f32x4 s[4];
#pragma unroll
  for (int nt = 0; nt < 4; ++nt) {
    bf16x8 bk = *(const bf16x8*)&sK[(nt * 16 + col) * 32 + g * 8];
    s[nt] = mfma16(aq, bk, fzero);
  }

  float p[4][4];
#pragma unroll
  for (int rr = 0; rr < 4; ++rr) {
    const int i = wv * 16 + g * 4 + rr;
    float mx = -1e30f;
#pragma unroll
    for (int nt = 0; nt < 4; ++nt) {
      const int j = nt * 16 + col;
      float val = s[nt][rr] + bf2f(sBias[i * 64 + j]);
      p[nt][rr] = val;
      mx = fmaxf(mx, val);
    }
#pragma unroll
    for (int d = 1; d < 16; d <<= 1) mx = fmaxf(mx, __shfl_xor(mx, d));
    float sm = 0.f;
#pragma unroll
    for (int nt = 0; nt < 4; ++nt) {
      float e = __expf(p[nt][rr] - mx);
      p[nt][rr] = e; sm += e;
    }
#pragma unroll
    for (int d = 1; d < 16; d <<= 1) sm += __shfl_xor(sm, d);
    const float inv = __builtin_amdgcn_rcpf(sm);
#pragma unroll
    for (int nt = 0; nt < 4; ++nt) p[nt][rr] *= inv;
  }
#pragma unroll
  for (int rr = 0; rr < 4; ++rr) {
    const int i = wv * 16 + g * 4 + rr;
#pragma unroll
    for (int nt = 0; nt < 4; ++nt) sP[i * 64 + nt * 16 + col] = f2bf(p[nt][rr]);
  }
  __syncthreads();

  f32x4 oa[2] = {fzero, fzero};
#pragma unroll
  for (int ks = 0; ks < 2; ++ks) {
    bf16x8 ap = *(const bf16x8*)&sP[(wv * 16 + col) * 64 + ks * 32 + g * 8];
#pragma unroll
    for (int n2 = 0; n2 < 2; ++n2) {
      bf16x8 bv = *(const bf16x8*)&sVT[(n2 * 16 + col) * 64 + ks * 32 + g * 8];
      oa[n2] = mfma16(ap, bv, oa[n2]);
    }
  }
#pragma unroll
  for (int rr = 0; rr < 4; ++rr) {
    const int i = wv * 16 + g * 4 + rr;
    if (i < 49) {
#pragma unroll
      for (int n2 = 0; n2 < 2; ++n2)
        o[((size_t)w * 49 + i) * 384 + h * 32 + n2 * 16 + col] = f2bf(oa[n2][rr]);
    }
  }
}

extern "C" void kernel_launch(void* const* d_in, const int* in_sizes, int n_in,
                              void* d_out, int out_size, void* d_ws, size_t ws_size,
                              hipStream_t stream) {
  (void)in_sizes; (void)n_in; (void)out_size; (void)ws_size;
  const float* s1   = (const float*)d_in[0];
  const float* s2   = (const float*)d_in[1];
  const float* mask = (const float*)d_in[2];
  const int*   rpi  = (const int*)d_in[3];
  const float* n1w1 = (const float*)d_in[4],  *n1b1 = (const float*)d_in[5];
  const float* n1w2 = (const float*)d_in[6],  *n1b2 = (const float*)d_in[7];
  const float* qw1  = (const float*)d_in[8],  *qb1  = (const float*)d_in[9];
  const float* qw2  = (const float*)d_in[10], *qb2  = (const float*)d_in[11];
  const float* rpb1 = (const float*)d_in[12];
  const float* pw1  = (const float*)d_in[14], *pb1  = (const float*)d_in[15];
  const float* n2w1 = (const float*)d_in[18], *n2b1 = (const float*)d_in[19];
  const float* n2w2 = (const float*)d_in[20], *n2b2 = (const float*)d_in[21];
  const float* m1fc1w = (const float*)d_in[22], *m1fc1b = (const float*)d_in[23];
  const float* m1fc2w = (const float*)d_in[24], *m1fc2b = (const float*)d_in[25];
  const float* m2fc1w = (const float*)d_in[26], *m2fc1b = (const float*)d_in[27];
  const float* m2fc2w = (const float*)d_in[28], *m2fc2b = (const float*)d_in[29];

  // R6-PROVEN layout: total = 5*S1 + 5.9MB ~= 198.6 MB (R7 lesson: don't exceed).
  char* ws = (char*)d_ws;
  const size_t S1 = (size_t)TOK * DIMC * 2;  // 38,535,168 B
  unsigned short* x1w  = (unsigned short*)(ws);        // later: obuf, xm
  unsigned short* x2w  = (unsigned short*)(ws + S1);   // later: biasb, then hbuf
  unsigned short* kv1  = (unsigned short*)(ws + 2 * S1);
  unsigned short* q2b  = (unsigned short*)(ws + 4 * S1);
  unsigned short* obuf = x1w;
  unsigned short* biasb = x2w;  // 25.2 MB <= S1
  unsigned short* hbuf = x2w;   // TOK x 1536 bf16 = 4*S1 (S1..5S1), overlays dead bufs
  unsigned short* xm   = x1w;
  char* wp = ws + 5 * S1;
  unsigned short* wq1b = (unsigned short*)(wp);
  unsigned short* wq2b = (unsigned short*)(wp + 589824);
  unsigned short* wp1b = (unsigned short*)(wp + 884736);
  unsigned short* wf11 = (unsigned short*)(wp + 1179648);
  unsigned short* wf12 = (unsigned short*)(wp + 2359296);
  unsigned short* wf21 = (unsigned short*)(wp + 3538944);
  unsigned short* wf22 = (unsigned short*)(wp + 4718592);

  float* outf = (float*)d_out;
  float* b1 = outf;
  float* b2 = outf + (size_t)19267584;

  // weights fp32 -> bf16 (qw1: k|v rows 384..1151 only)
  w2bf7_kern<<<11520, 256, 0, stream>>>(qw1 + 384 * 384, qw2, pw1,
                                        m1fc1w, m1fc2w, m2fc1w, m2fc2w,
                                        wq1b, wq2b, wp1b, wf11, wf12, wf21, wf22);

  // LN1 both branches + roll + window partition (one launch)
  ln2x_win_kern<<<2 * TOK / 4, 256, 0, stream>>>(s1, n1w1, n1b1, x1w,
                                                 s2, n1w2, n1b2, x2w);

  // merged qkv (seg0) + q2 (seg1, pre-scaled), 256-row tiles (VAR=1)
  gemm_bt<E_BF16, 1><<<1764, 256, 0, stream>>>(
      x1w, wq1b, qb1 + 384, kv1, nullptr, nullptr, nullptr, nullptr, 768, 6, 1176, 1.0f,
      x2w, wq2b, qb2, q2b, nullptr, nullptr, nullptr, nullptr, 384, 3, QSCALE, 384);

  // fused attention bias table (x2w now dead) then attention
  bias_kern<<<3072, 256, 0, stream>>>(rpi, mask, rpb1, biasb);
  attn_kern<<<dim3(1024, 12), 256, 0, stream>>>(q2b, kv1, biasb, obuf);

  // projection + window-reverse scatter + both residuals (VAR=0)
  gemm_bt<E_SCATTER, 0><<<1176, 256, 0, stream>>>(
      obuf, wp1b, pb1, nullptr, b1, b2, s1, s2, 384, 3, 1176, 1.0f,
      obuf, wp1b, pb1, nullptr, b1, b2, s1, s2, 384, 3, 1.0f, 384);

  // branch 1 MLP (fc1 VAR=1; fc2 VAR=0 — proven configs)
  ln_kern<<<TOK / 4, 256, 0, stream>>>(b1, n2w1, n2b1, xm);
  gemm_bt<E_GELU, 1><<<2352, 256, 0, stream>>>(
      xm, wf11, m1fc1b, hbuf, nullptr, nullptr, nullptr, nullptr, 1536, 12, 2352, 1.0f,
      xm, wf11, m1fc1b, hbuf, nullptr, nullptr, nullptr, nullptr, 1536, 12, 1.0f, 384);
  gemm_bt<E_RESOUT, 0><<<1176, 256, 0, stream>>>(
      hbuf, wf12, m1fc2b, nullptr, b1, nullptr, b1, nullptr, 384, 3, 1176, 1.0f,
      hbuf, wf12, m1fc2b, nullptr, b1, nullptr, b1, nullptr, 384, 3, 1.0f, 1536);

  // branch 2 MLP
  ln_kern<<<TOK / 4, 256, 0, stream>>>(b2, n2w2, n2b2, xm);
  gemm_bt<E_GELU, 1><<<2352, 256, 0, stream>>>(
      xm, wf21, m2fc1b, hbuf, nullptr, nullptr, nullptr, nullptr, 1536, 12, 2352, 1.0f,
      xm, wf21, m2fc1b, hbuf, nullptr, nullptr, nullptr, nullptr, 1536, 12, 1.0f, 384);
  gemm_bt<E_RESOUT, 0><<<1176, 256, 0, stream>>>(
      hbuf, wf22, m2fc2b, nullptr, b2, nullptr, b2, nullptr, 384, 3, 1176, 1.0f,
      hbuf, wf22, m2fc2b, nullptr, b2, nullptr, b2, nullptr, 384, 3, 1.0f, 1536);
}